// Round 2
// baseline (598.688 us; speedup 1.0000x reference)
//
#include <hip/hip_runtime.h>
#include <cmath>

#define DW 300
#define HH 128
#define G3 384
#define GN 768
#define SS 256
#define BBATCH 128
#define NC 10
#define DC 16
#define NCDC 160
#define CAP_EPS 1e-7f

__device__ __forceinline__ float sigmoidf_(float x) {
  return 1.0f / (1.0f + __expf(-x));
}
__device__ __forceinline__ float tanhf_(float x) {
  float e = __expf(2.0f * x);
  return 1.0f - 2.0f / (e + 1.0f);
}

// ---------------------------------------------------------------------------
// K1: xp[m][n] = sum_k emb[x(m)][k] * w(n)[k] + b_ih(n)
// m = s*128 + b ; n<384 -> forward weights, else backward.
// 128x128 tile, 8x8 acc/thread, K-panels of 60.
// ---------------------------------------------------------------------------
__global__ __launch_bounds__(256, 2) void k1_xproj(
    const int* __restrict__ x, const float* __restrict__ emb,
    const float* __restrict__ wf, const float* __restrict__ wb,
    const float* __restrict__ bf, const float* __restrict__ bb,
    float* __restrict__ xp)
{
  __shared__ __align__(16) float As[60][128];
  __shared__ __align__(16) float Bs[60][128];
  __shared__ int rows[128];
  const int tid = threadIdx.x;
  const int m0 = blockIdx.x * 128;
  const int n0 = blockIdx.y * 128;

  if (tid < 128) {
    const int m = m0 + tid;
    rows[tid] = x[(m & 127) * SS + (m >> 7)];
  }
  __syncthreads();

  const int lrow = tid & 127;
  const int lch  = tid >> 7;          // 0: float4 v=0..7, 1: v=8..14
  const int vbeg = lch ? 8 : 0;
  const int vend = lch ? 15 : 8;

  const float* __restrict__ arow = emb + (size_t)rows[lrow] * DW;
  const int nB = n0 + lrow;
  const float* __restrict__ brow =
      (nB < G3) ? (wf + (size_t)nB * DW) : (wb + (size_t)(nB - G3) * DW);

  const int tx = tid & 15;
  const int ty = tid >> 4;

  float acc[8][8] = {};

  for (int k0 = 0; k0 < DW; k0 += 60) {
    for (int v = vbeg; v < vend; ++v) {
      const float4 d = *(const float4*)(arow + k0 + 4 * v);
      As[4 * v + 0][lrow] = d.x; As[4 * v + 1][lrow] = d.y;
      As[4 * v + 2][lrow] = d.z; As[4 * v + 3][lrow] = d.w;
      const float4 e = *(const float4*)(brow + k0 + 4 * v);
      Bs[4 * v + 0][lrow] = e.x; Bs[4 * v + 1][lrow] = e.y;
      Bs[4 * v + 2][lrow] = e.z; Bs[4 * v + 3][lrow] = e.w;
    }
    __syncthreads();
#pragma unroll 6
    for (int k = 0; k < 60; ++k) {
      const float4 a0 = *(const float4*)&As[k][ty * 4];
      const float4 a1 = *(const float4*)&As[k][ty * 4 + 64];
      const float4 c0 = *(const float4*)&Bs[k][tx * 4];
      const float4 c1 = *(const float4*)&Bs[k][tx * 4 + 64];
      const float ar[8] = {a0.x, a0.y, a0.z, a0.w, a1.x, a1.y, a1.z, a1.w};
      const float bc[8] = {c0.x, c0.y, c0.z, c0.w, c1.x, c1.y, c1.z, c1.w};
#pragma unroll
      for (int i = 0; i < 8; ++i)
#pragma unroll
        for (int jj = 0; jj < 8; ++jj) acc[i][jj] += ar[i] * bc[jj];
    }
    __syncthreads();
  }

  // bias (whole 128-col tile lies on one side of the f/b split since 384%128==0)
  const float* __restrict__ bsrc = (n0 < G3) ? (bf + n0) : (bb + (n0 - G3));
  const float4 bias0 = *(const float4*)(bsrc + tx * 4);
  const float4 bias1 = *(const float4*)(bsrc + tx * 4 + 64);
  const float bb0[4] = {bias0.x, bias0.y, bias0.z, bias0.w};
  const float bb1[4] = {bias1.x, bias1.y, bias1.z, bias1.w};

#pragma unroll
  for (int hr = 0; hr < 2; ++hr) {
#pragma unroll
    for (int i = 0; i < 4; ++i) {
      const int m = m0 + ty * 4 + hr * 64 + i;
      float4 v0 = make_float4(acc[hr * 4 + i][0] + bb0[0], acc[hr * 4 + i][1] + bb0[1],
                              acc[hr * 4 + i][2] + bb0[2], acc[hr * 4 + i][3] + bb0[3]);
      float4 v1 = make_float4(acc[hr * 4 + i][4] + bb1[0], acc[hr * 4 + i][5] + bb1[1],
                              acc[hr * 4 + i][6] + bb1[2], acc[hr * 4 + i][7] + bb1[3]);
      *(float4*)&xp[(size_t)m * GN + n0 + tx * 4]      = v0;
      *(float4*)&xp[(size_t)m * GN + n0 + tx * 4 + 64] = v1;
    }
  }
}

// ---------------------------------------------------------------------------
// K2: GRU recurrence. One block per (dir, batch): 256 blocks x 1024 threads.
// 8 lanes per hidden unit j: roles 0-3 hold k-quarters of w_r AND w_n rows
// (shared h reads), roles 4-7 hold k-quarters of w_z (2nd field zero).
// shfl_xor reduce; role 0 does activations; double-buffered h -> 1 barrier/step.
// ---------------------------------------------------------------------------
__global__ __launch_bounds__(1024) void k2_gru(
    const float* __restrict__ xp,
    const float* __restrict__ whf, const float* __restrict__ whb,
    const float* __restrict__ bhf, const float* __restrict__ bhb,
    float* __restrict__ hcat)
{
  const int bid  = blockIdx.x;
  const int dir  = bid >> 7;
  const int b    = bid & 127;
  const int tid  = threadIdx.x;
  const int j    = tid >> 3;        // 0..127 hidden unit
  const int role = tid & 7;         // 0..7
  const int q    = role & 3;        // k-quarter
  const bool rn  = role < 4;        // roles 0-3: r & n rows; 4-7: z row

  const float* __restrict__ wh = dir ? whb : whf;
  const float* __restrict__ bh = dir ? bhb : bhf;

  float wa[32], wn[32];
  {
    const int rowA = rn ? j : (j + HH);          // r row or z row
    const float* srcA = wh + (size_t)rowA * HH + q * 32;
#pragma unroll
    for (int v = 0; v < 8; ++v) {
      const float4 d = *(const float4*)(srcA + 4 * v);
      wa[4 * v + 0] = d.x; wa[4 * v + 1] = d.y;
      wa[4 * v + 2] = d.z; wa[4 * v + 3] = d.w;
    }
    if (rn) {
      const float* srcB = wh + (size_t)(j + 2 * HH) * HH + q * 32;
#pragma unroll
      for (int v = 0; v < 8; ++v) {
        const float4 d = *(const float4*)(srcB + 4 * v);
        wn[4 * v + 0] = d.x; wn[4 * v + 1] = d.y;
        wn[4 * v + 2] = d.z; wn[4 * v + 3] = d.w;
      }
    } else {
#pragma unroll
      for (int i = 0; i < 32; ++i) wn[i] = 0.f;
    }
  }
  const float bhr = bh[j];
  const float bhz = bh[j + HH];
  const float bhn = bh[j + 2 * HH];

  __shared__ __align__(16) float hb[2][HH];
  for (int i = tid; i < 2 * HH; i += 1024) ((float*)hb)[i] = 0.f;
  __syncthreads();

  const float* __restrict__ xpd = xp + dir * G3;
  const int stp = dir ? -1 : 1;
  int s = dir ? (SS - 1) : 0;

  float xr = 0.f, xz = 0.f, xn = 0.f;
  if (role == 0) {
    const float* xbp = &xpd[((size_t)s * BBATCH + b) * GN + j];
    xr = xbp[0]; xz = xbp[HH]; xn = xbp[2 * HH];
  }

  int p = 0;
  for (int it = 0; it < SS; ++it) {
    const int s_cur = s;
    const float xr_c = xr, xz_c = xz, xn_c = xn;
    if (it < SS - 1) {
      s += stp;
      if (role == 0) {
        const float* xbp = &xpd[((size_t)s * BBATCH + b) * GN + j];
        xr = xbp[0]; xz = xbp[HH]; xn = xbp[2 * HH];   // prefetch next step
      }
    }

    float a0 = 0.f, a1 = 0.f, n0 = 0.f, n1 = 0.f;
    const float* hq = &hb[p][q * 32];
#pragma unroll
    for (int v = 0; v < 8; ++v) {
      const float4 h4 = *(const float4*)(hq + 4 * v);
      a0 += wa[4 * v + 0] * h4.x; a1 += wa[4 * v + 1] * h4.y;
      a0 += wa[4 * v + 2] * h4.z; a1 += wa[4 * v + 3] * h4.w;
      n0 += wn[4 * v + 0] * h4.x; n1 += wn[4 * v + 1] * h4.y;
      n0 += wn[4 * v + 2] * h4.z; n1 += wn[4 * v + 3] * h4.w;
    }
    float da = a0 + a1, dn = n0 + n1;
    da += __shfl_xor(da, 1); dn += __shfl_xor(dn, 1);
    da += __shfl_xor(da, 2); dn += __shfl_xor(dn, 2);
    // roles 0-3: da = dot_r, dn = dot_n ; roles 4-7: da = dot_z
    const float dz = __shfl_xor(da, 4);   // role0 <- role4's dot_z

    if (role == 0) {
      const float r    = sigmoidf_(xr_c + da + bhr);
      const float z    = sigmoidf_(xz_c + dz + bhz);
      const float n    = tanhf_(xn_c + r * (dn + bhn));
      const float hold = hb[p][j];
      const float hnew = (1.f - z) * n + z * hold;
      hb[p ^ 1][j] = hnew;
      hcat[((size_t)b * SS + s_cur) * 256 + dir * HH + j] = hnew;
    }
    p ^= 1;
    __syncthreads();
  }
}

// ---------------------------------------------------------------------------
// K3: uh[m][n] = sum_k hcat[m][k] * Wc[k][n]; m = b*256+s.
// ---------------------------------------------------------------------------
#define FMA16()                                                                \
  acc[0][0] += a.x * bv.x; acc[0][1] += a.x * bv.y;                            \
  acc[0][2] += a.x * bv.z; acc[0][3] += a.x * bv.w;                            \
  acc[1][0] += a.y * bv.x; acc[1][1] += a.y * bv.y;                            \
  acc[1][2] += a.y * bv.z; acc[1][3] += a.y * bv.w;                            \
  acc[2][0] += a.z * bv.x; acc[2][1] += a.z * bv.y;                            \
  acc[2][2] += a.z * bv.z; acc[2][3] += a.z * bv.w;                            \
  acc[3][0] += a.w * bv.x; acc[3][1] += a.w * bv.y;                            \
  acc[3][2] += a.w * bv.z; acc[3][3] += a.w * bv.w;

__global__ __launch_bounds__(256) void k3_uhat(
    const float* __restrict__ hcat, const float* __restrict__ Wc,
    float* __restrict__ uh)
{
  __shared__ __align__(16) float As[64][128];
  __shared__ __align__(16) float Bs[64][32];
  const int tid = threadIdx.x;
  const int m0 = blockIdx.x * 128;
  const int n0 = blockIdx.y * 32;
  const int tx = tid & 7;
  const int ty = tid >> 3;
  const int lr  = tid >> 1;
  const int lh  = tid & 1;
  const int bkr = tid >> 2;
  const int bq  = tid & 3;

  float acc[4][4] = {};

  for (int k0 = 0; k0 < 256; k0 += 64) {
    const float* asrc = hcat + (size_t)(m0 + lr) * 256 + k0 + lh * 32;
#pragma unroll
    for (int v = 0; v < 8; ++v) {
      const float4 d = *(const float4*)(asrc + 4 * v);
      const int kk = lh * 32 + 4 * v;
      As[kk + 0][lr] = d.x; As[kk + 1][lr] = d.y;
      As[kk + 2][lr] = d.z; As[kk + 3][lr] = d.w;
    }
    const float* bsrc = Wc + (size_t)(k0 + bkr) * NCDC + n0 + bq * 8;
    *(float4*)&Bs[bkr][bq * 8]     = *(const float4*)bsrc;
    *(float4*)&Bs[bkr][bq * 8 + 4] = *(const float4*)(bsrc + 4);
    __syncthreads();
#pragma unroll
    for (int k = 0; k < 64; ++k) {
      const float4 a  = *(const float4*)&As[k][ty * 4];
      const float4 bv = *(const float4*)&Bs[k][tx * 4];
      FMA16();
    }
    __syncthreads();
  }
#pragma unroll
  for (int i = 0; i < 4; ++i) {
    float4 v = make_float4(acc[i][0], acc[i][1], acc[i][2], acc[i][3]);
    *(float4*)&uh[(size_t)(m0 + ty * 4 + i) * NCDC + n0 + tx * 4] = v;
  }
}

// ---------------------------------------------------------------------------
// K4: dynamic routing + final linear. One block per batch element.
// ---------------------------------------------------------------------------
__global__ __launch_bounds__(256) void k4_route(
    const float* __restrict__ uhat, const float* __restrict__ Wl,
    const float* __restrict__ bl, float* __restrict__ outp)
{
  const int b = blockIdx.x;
  const int t = threadIdx.x;
  __shared__ float blog[NC][SS + 1];
  __shared__ float cbuf[NC][SS + 1];
  __shared__ float vout[NC][DC];
  __shared__ float red0[256], red1[256];

  const float* __restrict__ u = uhat + (size_t)b * SS * NCDC;

#pragma unroll
  for (int i = 0; i < NC; ++i) blog[i][t] = 0.f;
  __syncthreads();

  const int ci = t >> 4, ck = t & 15;
  float myval = 0.f;

  for (int it = 0; it < 5; ++it) {
    float m = blog[0][t];
#pragma unroll
    for (int i = 1; i < NC; ++i) m = fmaxf(m, blog[i][t]);
    float e[NC];
    float sum = 0.f;
#pragma unroll
    for (int i = 0; i < NC; ++i) { e[i] = __expf(blog[i][t] - m); sum += e[i]; }
    const float inv = 1.0f / sum;
#pragma unroll
    for (int i = 0; i < NC; ++i) cbuf[i][t] = e[i] * inv;
    __syncthreads();

    if (t < NCDC) {
      float acc = 0.f;
#pragma unroll 4
      for (int jj = 0; jj < SS; ++jj)
        acc += cbuf[ci][jj] * u[(size_t)jj * NCDC + t];
      float ss = acc * acc;
      ss += __shfl_xor(ss, 1);
      ss += __shfl_xor(ss, 2);
      ss += __shfl_xor(ss, 4);
      ss += __shfl_xor(ss, 8);
      myval = acc / sqrtf(ss + CAP_EPS);
      vout[ci][ck] = myval;
    }
    __syncthreads();

    if (it < 4) {
      const float* ur = u + (size_t)t * NCDC;
#pragma unroll
      for (int i = 0; i < NC; ++i) {
        float dot = 0.f;
#pragma unroll
        for (int k = 0; k < DC; ++k) dot += ur[i * DC + k] * vout[i][k];
        blog[i][t] += dot;
      }
      __syncthreads();
    }
  }

  float p0 = 0.f, p1 = 0.f;
  if (t < NCDC) { p0 = myval * Wl[2 * t]; p1 = myval * Wl[2 * t + 1]; }
  red0[t] = p0; red1[t] = p1;
  __syncthreads();
  for (int off = 128; off >= 1; off >>= 1) {
    if (t < off) { red0[t] += red0[t + off]; red1[t] += red1[t + off]; }
    __syncthreads();
  }
  if (t == 0) {
    outp[2 * b + 0] = red0[0] + bl[0];
    outp[2 * b + 1] = red1[0] + bl[1];
  }
}

extern "C" void kernel_launch(void* const* d_in, const int* in_sizes, int n_in,
                              void* d_out, int out_size, void* d_ws, size_t ws_size,
                              hipStream_t stream) {
  (void)in_sizes; (void)n_in; (void)out_size; (void)ws_size;
  const int*   x    = (const int*)  d_in[0];
  const float* emb  = (const float*)d_in[1];
  const float* wif  = (const float*)d_in[2];
  const float* whf  = (const float*)d_in[3];
  const float* bif  = (const float*)d_in[4];
  const float* bhf  = (const float*)d_in[5];
  const float* wib  = (const float*)d_in[6];
  const float* whb  = (const float*)d_in[7];
  const float* bib  = (const float*)d_in[8];
  const float* bhb  = (const float*)d_in[9];
  const float* Wc   = (const float*)d_in[10];
  const float* Wl   = (const float*)d_in[11];
  const float* bl   = (const float*)d_in[12];
  float* out = (float*)d_out;

  float* xp   = (float*)d_ws;                          // [32768][768]
  float* hcat = xp + (size_t)32768 * GN;               // [32768][256]
  float* uh   = hcat + (size_t)32768 * 256;            // [32768][160]

  dim3 g1(256, 6);
  hipLaunchKernelGGL(k1_xproj, g1, dim3(256), 0, stream, x, emb, wif, wib, bif, bib, xp);
  hipLaunchKernelGGL(k2_gru, dim3(256), dim3(1024), 0, stream, xp, whf, whb, bhf, bhb, hcat);
  dim3 g3(256, 5);
  hipLaunchKernelGGL(k3_uhat, g3, dim3(256), 0, stream, hcat, Wc, uh);
  hipLaunchKernelGGL(k4_route, dim3(128), dim3(256), 0, stream, uh, Wl, bl, out);
}

// Round 3
// 502.463 us; speedup vs baseline: 1.1915x; 1.1915x over previous
//
#include <hip/hip_runtime.h>
#include <cmath>

#define DW 300
#define HH 128
#define G3 384
#define GN 768
#define SS 256
#define BBATCH 128
#define NC 10
#define DC 16
#define NCDC 160
#define CAP_EPS 1e-7f

typedef _Float16 h8v __attribute__((ext_vector_type(8)));
typedef float f32x4 __attribute__((ext_vector_type(4)));

__device__ __forceinline__ float sigmoidf_(float x) {
  return 1.0f / (1.0f + __expf(-x));
}
__device__ __forceinline__ float tanhf_(float x) {
  float e = __expf(2.0f * x);
  return 1.0f - 2.0f / (e + 1.0f);
}

// LDS-only barrier: skip the vmcnt(0) drain __syncthreads() would emit, so
// in-flight global loads/stores survive across the barrier.
__device__ __forceinline__ void bar_lds() {
  asm volatile("s_waitcnt lgkmcnt(0)\n\ts_barrier" ::: "memory");
}

// ---------------------------------------------------------------------------
// K1: xp[m][n] = sum_k emb[x(m)][k] * w(n)[k] + b_ih(n), via fp16 MFMA.
// m = s*128 + b ; n<384 -> forward weights, else backward.
// 128x128 tile, BK=64, K padded 300->320 (zeros). Gather+f32->fp16 convert
// happens during staging; XOR-swizzled LDS (write & read) for ds_read_b128.
// ---------------------------------------------------------------------------
__global__ __launch_bounds__(256) void k1_xproj(
    const int* __restrict__ x, const float* __restrict__ emb,
    const float* __restrict__ wf, const float* __restrict__ wb,
    const float* __restrict__ bf, const float* __restrict__ bb,
    float* __restrict__ xp)
{
  __shared__ __align__(16) char Asb[128 * 64 * 2];
  __shared__ __align__(16) char Bsb[128 * 64 * 2];
  __shared__ int rows[128];

  const int tid = threadIdx.x;
  const int m0 = blockIdx.x * 128;
  const int n0 = blockIdx.y * 128;

  if (tid < 128) {
    const int m = m0 + tid;
    rows[tid] = x[(m & 127) * SS + (m >> 7)];
  }
  __syncthreads();

  const int colc  = tid & 7;    // 16B chunk within row (8 per 128B row)
  const int rbase = tid >> 3;   // 0..31

  const int lane = tid & 63;
  const int wv   = tid >> 6;    // 0..3
  const int wm   = wv >> 1;     // 0..1
  const int wn   = wv & 1;      // 0..1
  const int fr   = lane & 15;   // fragment row/col
  const int kc   = lane >> 4;   // k-chunk 0..3

  f32x4 acc[4][4];
#pragma unroll
  for (int i = 0; i < 4; ++i)
#pragma unroll
    for (int j = 0; j < 4; ++j) acc[i][j] = (f32x4){0.f, 0.f, 0.f, 0.f};

  const float* __restrict__ wside = (n0 < G3) ? wf : wb;
  const int nrel0 = (n0 < G3) ? n0 : (n0 - G3);

  for (int k0 = 0; k0 < DW; k0 += 64) {
    // ---- gather + convert to regs (overlaps previous MFMA via scheduler) ----
    h8v va[4], vb[4];
#pragma unroll
    for (int i = 0; i < 4; ++i) {
      const int r = i * 32 + rbase;
      const float* __restrict__ arow = emb + (size_t)rows[r] * DW;
      const float* __restrict__ brow = wside + (size_t)(nrel0 + r) * DW;
      const int kbase = k0 + colc * 8;
#pragma unroll
      for (int j = 0; j < 8; ++j) {
        const int k = kbase + j;
        va[i][j] = (_Float16)((k < DW) ? arow[k] : 0.f);
        vb[i][j] = (_Float16)((k < DW) ? brow[k] : 0.f);
      }
    }
    bar_lds();   // previous iteration's fragment reads done
#pragma unroll
    for (int i = 0; i < 4; ++i) {
      const int r = i * 32 + rbase;
      const int off = (r * 128 + colc * 16) ^ ((r & 7) << 4);
      *(h8v*)&Asb[off] = va[i];
      *(h8v*)&Bsb[off] = vb[i];
    }
    bar_lds();   // staged tile visible

    // ---- fragments + MFMA ----
    h8v af[4][2], bfr[4][2];
#pragma unroll
    for (int mf = 0; mf < 4; ++mf) {
      const int rA = wm * 64 + mf * 16 + fr;
#pragma unroll
      for (int ks = 0; ks < 2; ++ks) {
        const int off = (rA * 128 + ks * 64 + kc * 16) ^ ((rA & 7) << 4);
        af[mf][ks] = *(const h8v*)&Asb[off];
      }
    }
#pragma unroll
    for (int nf = 0; nf < 4; ++nf) {
      const int rB = wn * 64 + nf * 16 + fr;
#pragma unroll
      for (int ks = 0; ks < 2; ++ks) {
        const int off = (rB * 128 + ks * 64 + kc * 16) ^ ((rB & 7) << 4);
        bfr[nf][ks] = *(const h8v*)&Bsb[off];
      }
    }
#pragma unroll
    for (int ks = 0; ks < 2; ++ks)
#pragma unroll
      for (int mf = 0; mf < 4; ++mf)
#pragma unroll
        for (int nf = 0; nf < 4; ++nf)
          acc[mf][nf] = __builtin_amdgcn_mfma_f32_16x16x32_f16(
              af[mf][ks], bfr[nf][ks], acc[mf][nf], 0, 0, 0);
  }

  // ---- epilogue: bias + store ----
  const float* __restrict__ bsrc = (n0 < G3) ? (bf + n0) : (bb + (n0 - G3));
  float bval[4];
#pragma unroll
  for (int nf = 0; nf < 4; ++nf) bval[nf] = bsrc[wn * 64 + nf * 16 + fr];

#pragma unroll
  for (int mf = 0; mf < 4; ++mf) {
#pragma unroll
    for (int i = 0; i < 4; ++i) {
      const int m = m0 + wm * 64 + mf * 16 + kc * 4 + i;
      float* __restrict__ orow = xp + (size_t)m * GN + n0 + wn * 64 + fr;
#pragma unroll
      for (int nf = 0; nf < 4; ++nf)
        orow[nf * 16] = acc[mf][nf][i] + bval[nf];
    }
  }
}

// ---------------------------------------------------------------------------
// K2: GRU recurrence (round-1 structure + LDS-only barriers).
// One block per (dir, batch element): 256 blocks x 384 threads.
// Thread g holds w_hh row g in registers; h broadcast via LDS.
// ---------------------------------------------------------------------------
__global__ __launch_bounds__(384) void k2_gru(
    const float* __restrict__ xp,
    const float* __restrict__ whf, const float* __restrict__ whb,
    const float* __restrict__ bhf, const float* __restrict__ bhb,
    float* __restrict__ hcat)
{
  const int bid = blockIdx.x;
  const int dir = bid >> 7;
  const int b   = bid & 127;
  const int g   = threadIdx.x;   // 0..383
  const int grp = g >> 7;        // 0:r 1:z 2:n
  const int j   = g & 127;

  const float* __restrict__ wh = dir ? whb : whf;
  const float* __restrict__ bh = dir ? bhb : bhf;

  float w[128];
  {
    const float* src = wh + (size_t)g * HH;
#pragma unroll
    for (int v = 0; v < 32; ++v) {
      const float4 d = *(const float4*)(src + 4 * v);
      w[4 * v + 0] = d.x; w[4 * v + 1] = d.y;
      w[4 * v + 2] = d.z; w[4 * v + 3] = d.w;
    }
  }
  const float bias = bh[g];

  __shared__ __align__(16) float hbuf[HH];
  __shared__ float rbuf[HH];
  __shared__ float zbuf[HH];
  if (g < HH) hbuf[g] = 0.f;
  __syncthreads();

  const float* __restrict__ xpd = xp + dir * G3;
  const int step = dir ? -1 : 1;
  int s = dir ? (SS - 1) : 0;
  float xg = xpd[((size_t)s * BBATCH + b) * GN + g];

  for (int it = 0; it < SS; ++it) {
    const int s_cur = s;
    const float xcur = xg;
    if (it < SS - 1) {
      s += step;
      xg = xpd[((size_t)s * BBATCH + b) * GN + g];   // prefetch next step
    }
    float d0 = 0.f, d1 = 0.f, d2 = 0.f, d3 = 0.f;
#pragma unroll
    for (int v = 0; v < 32; ++v) {
      const float4 h4 = *(const float4*)&hbuf[4 * v];
      d0 += w[4 * v + 0] * h4.x;
      d1 += w[4 * v + 1] * h4.y;
      d2 += w[4 * v + 2] * h4.z;
      d3 += w[4 * v + 3] * h4.w;
    }
    const float hp = (d0 + d1) + (d2 + d3) + bias;
    if (grp == 0) {
      rbuf[j] = sigmoidf_(xcur + hp);
    } else if (grp == 1) {
      zbuf[j] = sigmoidf_(xcur + hp);
    }
    bar_lds();
    if (grp == 2) {
      const float r = rbuf[j];
      const float n = tanhf_(xcur + r * hp);
      const float z = zbuf[j];
      const float hnew = (1.f - z) * n + z * hbuf[j];
      hbuf[j] = hnew;
      hcat[((size_t)b * SS + s_cur) * 256 + dir * HH + j] = hnew;
    }
    bar_lds();
  }
}

// ---------------------------------------------------------------------------
// K3: uh[m][n] = sum_k hcat[m][k] * Wc[k][n]; m = b*256+s.
// ---------------------------------------------------------------------------
#define FMA16()                                                                \
  acc[0][0] += a.x * bv.x; acc[0][1] += a.x * bv.y;                            \
  acc[0][2] += a.x * bv.z; acc[0][3] += a.x * bv.w;                            \
  acc[1][0] += a.y * bv.x; acc[1][1] += a.y * bv.y;                            \
  acc[1][2] += a.y * bv.z; acc[1][3] += a.y * bv.w;                            \
  acc[2][0] += a.z * bv.x; acc[2][1] += a.z * bv.y;                            \
  acc[2][2] += a.z * bv.z; acc[2][3] += a.z * bv.w;                            \
  acc[3][0] += a.w * bv.x; acc[3][1] += a.w * bv.y;                            \
  acc[3][2] += a.w * bv.z; acc[3][3] += a.w * bv.w;

__global__ __launch_bounds__(256) void k3_uhat(
    const float* __restrict__ hcat, const float* __restrict__ Wc,
    float* __restrict__ uh)
{
  __shared__ __align__(16) float As[64][128];
  __shared__ __align__(16) float Bs[64][32];
  const int tid = threadIdx.x;
  const int m0 = blockIdx.x * 128;
  const int n0 = blockIdx.y * 32;
  const int tx = tid & 7;
  const int ty = tid >> 3;
  const int lr  = tid >> 1;
  const int lh  = tid & 1;
  const int bkr = tid >> 2;
  const int bq  = tid & 3;

  float acc[4][4] = {};

  for (int k0 = 0; k0 < 256; k0 += 64) {
    const float* asrc = hcat + (size_t)(m0 + lr) * 256 + k0 + lh * 32;
#pragma unroll
    for (int v = 0; v < 8; ++v) {
      const float4 d = *(const float4*)(asrc + 4 * v);
      const int kk = lh * 32 + 4 * v;
      As[kk + 0][lr] = d.x; As[kk + 1][lr] = d.y;
      As[kk + 2][lr] = d.z; As[kk + 3][lr] = d.w;
    }
    const float* bsrc = Wc + (size_t)(k0 + bkr) * NCDC + n0 + bq * 8;
    *(float4*)&Bs[bkr][bq * 8]     = *(const float4*)bsrc;
    *(float4*)&Bs[bkr][bq * 8 + 4] = *(const float4*)(bsrc + 4);
    __syncthreads();
#pragma unroll
    for (int k = 0; k < 64; ++k) {
      const float4 a  = *(const float4*)&As[k][ty * 4];
      const float4 bv = *(const float4*)&Bs[k][tx * 4];
      FMA16();
    }
    __syncthreads();
  }
#pragma unroll
  for (int i = 0; i < 4; ++i) {
    float4 v = make_float4(acc[i][0], acc[i][1], acc[i][2], acc[i][3]);
    *(float4*)&uh[(size_t)(m0 + ty * 4 + i) * NCDC + n0 + tx * 4] = v;
  }
}

// ---------------------------------------------------------------------------
// K4: dynamic routing + final linear. One block per batch element.
// ---------------------------------------------------------------------------
__global__ __launch_bounds__(256) void k4_route(
    const float* __restrict__ uhat, const float* __restrict__ Wl,
    const float* __restrict__ bl, float* __restrict__ outp)
{
  const int b = blockIdx.x;
  const int t = threadIdx.x;
  __shared__ float blog[NC][SS + 1];
  __shared__ float cbuf[NC][SS + 1];
  __shared__ float vout[NC][DC];
  __shared__ float red0[256], red1[256];

  const float* __restrict__ u = uhat + (size_t)b * SS * NCDC;

#pragma unroll
  for (int i = 0; i < NC; ++i) blog[i][t] = 0.f;
  __syncthreads();

  const int ci = t >> 4, ck = t & 15;
  float myval = 0.f;

  for (int it = 0; it < 5; ++it) {
    float m = blog[0][t];
#pragma unroll
    for (int i = 1; i < NC; ++i) m = fmaxf(m, blog[i][t]);
    float e[NC];
    float sum = 0.f;
#pragma unroll
    for (int i = 0; i < NC; ++i) { e[i] = __expf(blog[i][t] - m); sum += e[i]; }
    const float inv = 1.0f / sum;
#pragma unroll
    for (int i = 0; i < NC; ++i) cbuf[i][t] = e[i] * inv;
    __syncthreads();

    if (t < NCDC) {
      float acc = 0.f;
#pragma unroll 4
      for (int jj = 0; jj < SS; ++jj)
        acc += cbuf[ci][jj] * u[(size_t)jj * NCDC + t];
      float ss = acc * acc;
      ss += __shfl_xor(ss, 1);
      ss += __shfl_xor(ss, 2);
      ss += __shfl_xor(ss, 4);
      ss += __shfl_xor(ss, 8);
      myval = acc / sqrtf(ss + CAP_EPS);
      vout[ci][ck] = myval;
    }
    __syncthreads();

    if (it < 4) {
      const float* ur = u + (size_t)t * NCDC;
#pragma unroll
      for (int i = 0; i < NC; ++i) {
        float dot = 0.f;
#pragma unroll
        for (int k = 0; k < DC; ++k) dot += ur[i * DC + k] * vout[i][k];
        blog[i][t] += dot;
      }
      __syncthreads();
    }
  }

  float p0 = 0.f, p1 = 0.f;
  if (t < NCDC) { p0 = myval * Wl[2 * t]; p1 = myval * Wl[2 * t + 1]; }
  red0[t] = p0; red1[t] = p1;
  __syncthreads();
  for (int off = 128; off >= 1; off >>= 1) {
    if (t < off) { red0[t] += red0[t + off]; red1[t] += red1[t + off]; }
    __syncthreads();
  }
  if (t == 0) {
    outp[2 * b + 0] = red0[0] + bl[0];
    outp[2 * b + 1] = red1[0] + bl[1];
  }
}

extern "C" void kernel_launch(void* const* d_in, const int* in_sizes, int n_in,
                              void* d_out, int out_size, void* d_ws, size_t ws_size,
                              hipStream_t stream) {
  (void)in_sizes; (void)n_in; (void)out_size; (void)ws_size;
  const int*   x    = (const int*)  d_in[0];
  const float* emb  = (const float*)d_in[1];
  const float* wif  = (const float*)d_in[2];
  const float* whf  = (const float*)d_in[3];
  const float* bif  = (const float*)d_in[4];
  const float* bhf  = (const float*)d_in[5];
  const float* wib  = (const float*)d_in[6];
  const float* whb  = (const float*)d_in[7];
  const float* bib  = (const float*)d_in[8];
  const float* bhb  = (const float*)d_in[9];
  const float* Wc   = (const float*)d_in[10];
  const float* Wl   = (const float*)d_in[11];
  const float* bl   = (const float*)d_in[12];
  float* out = (float*)d_out;

  float* xp   = (float*)d_ws;                          // [32768][768]
  float* hcat = xp + (size_t)32768 * GN;               // [32768][256]
  float* uh   = hcat + (size_t)32768 * 256;            // [32768][160]

  dim3 g1(256, 6);
  hipLaunchKernelGGL(k1_xproj, g1, dim3(256), 0, stream, x, emb, wif, wib, bif, bib, xp);
  hipLaunchKernelGGL(k2_gru, dim3(256), dim3(384), 0, stream, xp, whf, whb, bhf, bhb, hcat);
  dim3 g3(256, 5);
  hipLaunchKernelGGL(k3_uhat, g3, dim3(256), 0, stream, hcat, Wc, uh);
  hipLaunchKernelGGL(k4_route, dim3(128), dim3(256), 0, stream, uh, Wl, bl, out);
}

// Round 4
// 486.506 us; speedup vs baseline: 1.2306x; 1.0328x over previous
//
#include <hip/hip_runtime.h>
#include <cmath>

#define DW 300
#define HH 128
#define G3 384
#define GN 768
#define SS 256
#define NB 128
#define NC 10
#define DC 16
#define NCDC 160
#define CAP_EPS 1e-7f
#define KP 320

typedef _Float16 h8v __attribute__((ext_vector_type(8)));
typedef _Float16 h4v __attribute__((ext_vector_type(4)));
typedef float f32x4 __attribute__((ext_vector_type(4)));

__device__ __forceinline__ float sigmoidf_(float x) {
  return 1.0f / (1.0f + __expf(-x));
}
__device__ __forceinline__ float tanhf_(float x) {
  float e = __expf(2.0f * x);
  return 1.0f - 2.0f / (e + 1.0f);
}
// LDS-only barrier: don't drain vmcnt, so global loads/stores stay in flight.
__device__ __forceinline__ void bar_lds() {
  asm volatile("s_waitcnt lgkmcnt(0)\n\ts_barrier" ::: "memory");
}

// ---------------------------------------------------------------------------
// K0: gather emb rows -> A16[32768][320] fp16 (K padded 300->320 with zeros),
// convert w_ih (f+b) -> Bw16[768][320], transpose W_cap -> WcT[160][256].
// ---------------------------------------------------------------------------
__global__ __launch_bounds__(64) void k0_prep(
    const int* __restrict__ x, const float* __restrict__ emb,
    const float* __restrict__ wif, const float* __restrict__ wib,
    const float* __restrict__ Wc,
    _Float16* __restrict__ A16, _Float16* __restrict__ Bw16,
    _Float16* __restrict__ WcT)
{
  const int row = blockIdx.x;
  const int t = threadIdx.x;
  if (row < 33536) {
    const float* __restrict__ src;
    _Float16* __restrict__ dst;
    if (row < 32768) {
      src = emb + (size_t)x[(row & 127) * SS + (row >> 7)] * DW;
      dst = A16 + (size_t)row * KP;
    } else {
      const int n = row - 32768;
      src = (n < G3) ? (wif + (size_t)n * DW) : (wib + (size_t)(n - G3) * DW);
      dst = Bw16 + (size_t)n * KP;
    }
#pragma unroll
    for (int p = 0; p < 2; ++p) {
      const int idx = p * 64 + t;
      if (idx < 75) {
        const float4 v = *(const float4*)(src + idx * 4);
        h4v o = {(_Float16)v.x, (_Float16)v.y, (_Float16)v.z, (_Float16)v.w};
        *(h4v*)(dst + idx * 4) = o;
      }
    }
    if (t < 5) {
      h4v z = {(_Float16)0.f, (_Float16)0.f, (_Float16)0.f, (_Float16)0.f};
      *(h4v*)(dst + 300 + t * 4) = z;
    }
  } else {
    const int n = row - 33536;   // 0..159
    _Float16* __restrict__ dst = WcT + (size_t)n * 256;
#pragma unroll
    for (int p = 0; p < 4; ++p) {
      const int k = p * 64 + t;
      dst[k] = (_Float16)Wc[(size_t)k * NCDC + n];
    }
  }
}

// ---------------------------------------------------------------------------
// K1: xpT[n][m] = sum_k A16[m][k]*Bw16[n][k] + b_ih(n)   (fp16 MFMA GEMM)
// 128x128 tile, BK=64, 4 waves (2x2 quadrants of 64x64), swizzled LDS.
// Output written TRANSPOSED: xpT[768][32768] for k2's coalesced reads.
// ---------------------------------------------------------------------------
__global__ __launch_bounds__(256) void k1_xproj(
    const _Float16* __restrict__ A16, const _Float16* __restrict__ Bw16,
    const float* __restrict__ bf, const float* __restrict__ bb,
    float* __restrict__ xpT)
{
  __shared__ __align__(16) _Float16 Asb[128 * 64];
  __shared__ __align__(16) _Float16 Bsb[128 * 64];
  const int tid = threadIdx.x;
  const int m0 = blockIdx.x * 128;
  const int n0 = blockIdx.y * 128;
  const int lane = tid & 63;
  const int wv = tid >> 6, wm = wv >> 1, wn = wv & 1;
  const int fr = lane & 15, kc4 = lane >> 4;

  const int srow = tid >> 3;   // 0..31 (+i*32)
  const int sch  = tid & 7;    // 16B chunk within 128B row

  f32x4 acc[4][4];
#pragma unroll
  for (int i = 0; i < 4; ++i)
#pragma unroll
    for (int j = 0; j < 4; ++j) acc[i][j] = (f32x4){0.f, 0.f, 0.f, 0.f};

  h8v ra[4], rb[4];
#pragma unroll
  for (int i = 0; i < 4; ++i) {
    const int r = i * 32 + srow;
    ra[i] = *(const h8v*)(A16 + (size_t)(m0 + r) * KP + sch * 8);
    rb[i] = *(const h8v*)(Bw16 + (size_t)(n0 + r) * KP + sch * 8);
  }

  for (int kt = 0; kt < 5; ++kt) {
    if (kt) bar_lds();                    // prev frag reads done
#pragma unroll
    for (int i = 0; i < 4; ++i) {
      const int r = i * 32 + srow;
      const int off = (r * 128 + sch * 16) ^ ((r & 7) << 4);
      *(h8v*)((char*)Asb + off) = ra[i];
      *(h8v*)((char*)Bsb + off) = rb[i];
    }
    if (kt < 4) {
      const int kb = (kt + 1) * 64;
#pragma unroll
      for (int i = 0; i < 4; ++i) {
        const int r = i * 32 + srow;
        ra[i] = *(const h8v*)(A16 + (size_t)(m0 + r) * KP + kb + sch * 8);
        rb[i] = *(const h8v*)(Bw16 + (size_t)(n0 + r) * KP + kb + sch * 8);
      }
    }
    bar_lds();                            // staged tile visible

    h8v af[4][2], bfv[4][2];
#pragma unroll
    for (int mf = 0; mf < 4; ++mf) {
      const int rA = wm * 64 + mf * 16 + fr;
#pragma unroll
      for (int ks = 0; ks < 2; ++ks) {
        const int off = (rA * 128 + ks * 64 + kc4 * 16) ^ ((rA & 7) << 4);
        af[mf][ks] = *(const h8v*)((const char*)Asb + off);
      }
    }
#pragma unroll
    for (int nf = 0; nf < 4; ++nf) {
      const int rB = wn * 64 + nf * 16 + fr;
#pragma unroll
      for (int ks = 0; ks < 2; ++ks) {
        const int off = (rB * 128 + ks * 64 + kc4 * 16) ^ ((rB & 7) << 4);
        bfv[nf][ks] = *(const h8v*)((const char*)Bsb + off);
      }
    }
#pragma unroll
    for (int ks = 0; ks < 2; ++ks)
#pragma unroll
      for (int mf = 0; mf < 4; ++mf)
#pragma unroll
        for (int nf = 0; nf < 4; ++nf)
          acc[mf][nf] = __builtin_amdgcn_mfma_f32_16x16x32_f16(
              af[mf][ks], bfv[nf][ks], acc[mf][nf], 0, 0, 0);
  }

  const float* __restrict__ bsrc = (n0 < G3) ? (bf + n0) : (bb + (n0 - G3));
#pragma unroll
  for (int nf = 0; nf < 4; ++nf) {
    const int n = n0 + wn * 64 + nf * 16 + fr;
    const float bias = bsrc[wn * 64 + nf * 16 + fr];
#pragma unroll
    for (int mf = 0; mf < 4; ++mf) {
      f32x4 v = acc[mf][nf];
      v[0] += bias; v[1] += bias; v[2] += bias; v[3] += bias;
      *(f32x4*)(xpT + (size_t)n * 32768 + m0 + wm * 64 + mf * 16 + kc4 * 4) = v;
    }
  }
}

// ---------------------------------------------------------------------------
// K2: GRU recurrence via MFMA. 16 blocks = (dir, batch-tile of 16) x 4 waves.
// Wave w holds w_hh^T fragments for j-tiles {2w,2w+1} persistently in VGPRs.
// Per step: h[16x128] fp16 in (swizzled) LDS -> A-frags; D = h @ w_hh^T;
// gate math on f32 master state; h_new -> LDS fp16 + hcat16 global.
// ---------------------------------------------------------------------------
__global__ __launch_bounds__(256) void k2_gru(
    const float* __restrict__ xpT,
    const float* __restrict__ whf, const float* __restrict__ whb,
    const float* __restrict__ bhf, const float* __restrict__ bhb,
    _Float16* __restrict__ hcat16)
{
  const int blk = blockIdx.x;
  const int dir = blk >> 3;
  const int btile = blk & 7;
  const int tid = threadIdx.x;
  const int lane = tid & 63;
  const int wv = tid >> 6;
  const int fr = lane & 15;
  const int qq = lane >> 4;

  const float* __restrict__ wh = dir ? whb : whf;
  const float* __restrict__ bh = dir ? bhb : bhf;

  h8v wB[2][3][4];
  float bias_r[2], bias_z[2], bias_n[2];
#pragma unroll
  for (int jt = 0; jt < 2; ++jt) {
    const int jg = 2 * wv + jt;
#pragma unroll
    for (int G = 0; G < 3; ++G) {
      const int row = G * HH + jg * 16 + fr;
      const float* __restrict__ p = wh + (size_t)row * HH;
#pragma unroll
      for (int kc = 0; kc < 4; ++kc) {
        const float* q = p + kc * 32 + qq * 8;
        const float4 u0 = *(const float4*)(q);
        const float4 u1 = *(const float4*)(q + 4);
        wB[jt][G][kc] = (h8v){(_Float16)u0.x, (_Float16)u0.y, (_Float16)u0.z,
                              (_Float16)u0.w, (_Float16)u1.x, (_Float16)u1.y,
                              (_Float16)u1.z, (_Float16)u1.w};
      }
    }
    bias_r[jt] = bh[0 * HH + jg * 16 + fr];
    bias_z[jt] = bh[1 * HH + jg * 16 + fr];
    bias_n[jt] = bh[2 * HH + jg * 16 + fr];
  }

  __shared__ __align__(16) _Float16 h16[16 * 128];   // 4KB, swizzled
  *(f32x4*)((char*)h16 + tid * 16) = (f32x4){0.f, 0.f, 0.f, 0.f};

  f32x4 hold[2] = {{0.f, 0.f, 0.f, 0.f}, {0.f, 0.f, 0.f, 0.f}};

  const float* __restrict__ xrow[2][3];
#pragma unroll
  for (int jt = 0; jt < 2; ++jt)
#pragma unroll
    for (int G = 0; G < 3; ++G)
      xrow[jt][G] = xpT +
          (size_t)(dir * G3 + G * HH + (2 * wv + jt) * 16 + fr) * 32768 +
          btile * 16 + qq * 4;

  __syncthreads();

  int s = dir ? (SS - 1) : 0;
  const int stp = dir ? -1 : 1;

  f32x4 xp_[2][3];
#pragma unroll
  for (int jt = 0; jt < 2; ++jt)
#pragma unroll
    for (int G = 0; G < 3; ++G)
      xp_[jt][G] = *(const f32x4*)(xrow[jt][G] + s * NB);

  for (int it = 0; it < SS; ++it) {
    const int s_cur = s;
    // A fragments (h) from swizzled LDS
    h8v afr[4];
#pragma unroll
    for (int kc = 0; kc < 4; ++kc) {
      const int off = (fr * 256 + kc * 64 + qq * 16) ^ ((fr & 7) << 4);
      afr[kc] = *(const h8v*)((const char*)h16 + off);
    }
    f32x4 xc[2][3];
#pragma unroll
    for (int jt = 0; jt < 2; ++jt)
#pragma unroll
      for (int G = 0; G < 3; ++G) xc[jt][G] = xp_[jt][G];
    if (it < SS - 1) {
      s += stp;
#pragma unroll
      for (int jt = 0; jt < 2; ++jt)
#pragma unroll
        for (int G = 0; G < 3; ++G)
          xp_[jt][G] = *(const f32x4*)(xrow[jt][G] + s * NB);
    }

    f32x4 acc[2][3];
#pragma unroll
    for (int jt = 0; jt < 2; ++jt) {
      acc[jt][0] = xc[jt][0];
      acc[jt][0][0] += bias_r[jt]; acc[jt][0][1] += bias_r[jt];
      acc[jt][0][2] += bias_r[jt]; acc[jt][0][3] += bias_r[jt];
      acc[jt][1] = xc[jt][1];
      acc[jt][1][0] += bias_z[jt]; acc[jt][1][1] += bias_z[jt];
      acc[jt][1][2] += bias_z[jt]; acc[jt][1][3] += bias_z[jt];
      acc[jt][2] = (f32x4){bias_n[jt], bias_n[jt], bias_n[jt], bias_n[jt]};
#pragma unroll
      for (int G = 0; G < 3; ++G)
#pragma unroll
        for (int kc = 0; kc < 4; ++kc)
          acc[jt][G] = __builtin_amdgcn_mfma_f32_16x16x32_f16(
              afr[kc], wB[jt][G][kc], acc[jt][G], 0, 0, 0);
    }

    bar_lds();   // all waves' A-frag reads complete

#pragma unroll
    for (int jt = 0; jt < 2; ++jt) {
      f32x4 hn;
#pragma unroll
      for (int e = 0; e < 4; ++e) {
        const float r = sigmoidf_(acc[jt][0][e]);
        const float z = sigmoidf_(acc[jt][1][e]);
        const float n = tanhf_(xc[jt][2][e] + r * acc[jt][2][e]);
        hn[e] = (1.f - z) * n + z * hold[jt][e];
      }
      hold[jt] = hn;
      const int j = (2 * wv + jt) * 16 + fr;
#pragma unroll
      for (int e = 0; e < 4; ++e) {
        const int bl = qq * 4 + e;
        const _Float16 hv = (_Float16)hn[e];
        const int off = (bl * 256 + j * 2) ^ ((bl & 7) << 4);
        *(_Float16*)((char*)h16 + off) = hv;
        hcat16[((size_t)(btile * 16 + bl) * SS + s_cur) * 256 + dir * HH + j] = hv;
      }
    }
    bar_lds();   // h_new visible for next step
  }
}

// ---------------------------------------------------------------------------
// K3: uh[m][n] = sum_k hcat16[m][k] * Wc[k][n]  (fp16 MFMA)
// 128xM tile x full N=160, K=256 staged whole in 64KB swizzled LDS.
// ---------------------------------------------------------------------------
__global__ __launch_bounds__(256) void k3_uhat(
    const _Float16* __restrict__ hcat16, const _Float16* __restrict__ WcT,
    float* __restrict__ uh)
{
  __shared__ __align__(16) _Float16 Hs[128 * 256];   // 64KB
  const int tid = threadIdx.x;
  const int m0 = blockIdx.x * 128;
  const int lane = tid & 63, wv = tid >> 6;
  const int fr = lane & 15, qq = lane >> 4;

  const int srow = tid >> 5;   // 0..7
  const int sch  = tid & 31;   // 16B chunk of 512B row
#pragma unroll
  for (int i = 0; i < 16; ++i) {
    const int r = i * 8 + srow;
    const h8v v = *(const h8v*)(hcat16 + (size_t)(m0 + r) * 256 + sch * 8);
    const int off = (r * 512 + sch * 16) ^ ((r & 7) << 4);
    *(h8v*)((char*)Hs + off) = v;
  }
  __syncthreads();

  f32x4 acc[2][10];
#pragma unroll
  for (int mt = 0; mt < 2; ++mt)
#pragma unroll
    for (int nt = 0; nt < 10; ++nt) acc[mt][nt] = (f32x4){0.f, 0.f, 0.f, 0.f};

#pragma unroll
  for (int kc = 0; kc < 8; ++kc) {
    h8v bf_[10];
#pragma unroll
    for (int nt = 0; nt < 10; ++nt)
      bf_[nt] = *(const h8v*)(WcT + (size_t)(nt * 16 + fr) * 256 + kc * 32 + qq * 8);
    h8v af[2];
#pragma unroll
    for (int mt = 0; mt < 2; ++mt) {
      const int rA = wv * 32 + mt * 16 + fr;
      const int off = (rA * 512 + kc * 64 + qq * 16) ^ ((rA & 7) << 4);
      af[mt] = *(const h8v*)((const char*)Hs + off);
    }
#pragma unroll
    for (int mt = 0; mt < 2; ++mt)
#pragma unroll
      for (int nt = 0; nt < 10; ++nt)
        acc[mt][nt] = __builtin_amdgcn_mfma_f32_16x16x32_f16(
            af[mt], bf_[nt], acc[mt][nt], 0, 0, 0);
  }

#pragma unroll
  for (int mt = 0; mt < 2; ++mt)
#pragma unroll
    for (int nt = 0; nt < 10; ++nt)
#pragma unroll
      for (int e = 0; e < 4; ++e) {
        const int m = m0 + wv * 32 + mt * 16 + qq * 4 + e;
        uh[(size_t)m * NCDC + nt * 16 + fr] = acc[mt][nt][e];
      }
}

// ---------------------------------------------------------------------------
// K4: dynamic routing + final linear. One block per batch element.
// ---------------------------------------------------------------------------
__global__ __launch_bounds__(256) void k4_route(
    const float* __restrict__ uhat, const float* __restrict__ Wl,
    const float* __restrict__ bl, float* __restrict__ outp)
{
  const int b = blockIdx.x;
  const int t = threadIdx.x;
  __shared__ float blog[NC][SS + 1];
  __shared__ float cbuf[NC][SS + 1];
  __shared__ float vout[NC][DC];
  __shared__ float red0[256], red1[256];

  const float* __restrict__ u = uhat + (size_t)b * SS * NCDC;

#pragma unroll
  for (int i = 0; i < NC; ++i) blog[i][t] = 0.f;
  __syncthreads();

  const int ci = t >> 4, ck = t & 15;
  float myval = 0.f;

  for (int it = 0; it < 5; ++it) {
    float m = blog[0][t];
#pragma unroll
    for (int i = 1; i < NC; ++i) m = fmaxf(m, blog[i][t]);
    float e[NC];
    float sum = 0.f;
#pragma unroll
    for (int i = 0; i < NC; ++i) { e[i] = __expf(blog[i][t] - m); sum += e[i]; }
    const float inv = 1.0f / sum;
#pragma unroll
    for (int i = 0; i < NC; ++i) cbuf[i][t] = e[i] * inv;
    __syncthreads();

    if (t < NCDC) {
      float acc = 0.f;
#pragma unroll 4
      for (int jj = 0; jj < SS; ++jj)
        acc += cbuf[ci][jj] * u[(size_t)jj * NCDC + t];
      float ss = acc * acc;
      ss += __shfl_xor(ss, 1);
      ss += __shfl_xor(ss, 2);
      ss += __shfl_xor(ss, 4);
      ss += __shfl_xor(ss, 8);
      myval = acc / sqrtf(ss + CAP_EPS);
      vout[ci][ck] = myval;
    }
    __syncthreads();

    if (it < 4) {
      const float* ur = u + (size_t)t * NCDC;
#pragma unroll
      for (int i = 0; i < NC; ++i) {
        float dot = 0.f;
#pragma unroll
        for (int k = 0; k < DC; ++k) dot += ur[i * DC + k] * vout[i][k];
        blog[i][t] += dot;
      }
      __syncthreads();
    }
  }

  float p0 = 0.f, p1 = 0.f;
  if (t < NCDC) { p0 = myval * Wl[2 * t]; p1 = myval * Wl[2 * t + 1]; }
  red0[t] = p0; red1[t] = p1;
  __syncthreads();
  for (int off = 128; off >= 1; off >>= 1) {
    if (t < off) { red0[t] += red0[t + off]; red1[t] += red1[t + off]; }
    __syncthreads();
  }
  if (t == 0) {
    outp[2 * b + 0] = red0[0] + bl[0];
    outp[2 * b + 1] = red1[0] + bl[1];
  }
}

extern "C" void kernel_launch(void* const* d_in, const int* in_sizes, int n_in,
                              void* d_out, int out_size, void* d_ws, size_t ws_size,
                              hipStream_t stream) {
  (void)in_sizes; (void)n_in; (void)out_size; (void)ws_size;
  const int*   x    = (const int*)  d_in[0];
  const float* emb  = (const float*)d_in[1];
  const float* wif  = (const float*)d_in[2];
  const float* whf  = (const float*)d_in[3];
  const float* bif  = (const float*)d_in[4];
  const float* bhf  = (const float*)d_in[5];
  const float* wib  = (const float*)d_in[6];
  const float* whb  = (const float*)d_in[7];
  const float* bib  = (const float*)d_in[8];
  const float* bhb  = (const float*)d_in[9];
  const float* Wc   = (const float*)d_in[10];
  const float* Wl   = (const float*)d_in[11];
  const float* bl   = (const float*)d_in[12];
  float* out = (float*)d_out;

  char* base = (char*)d_ws;
  float*     xpT    = (float*)base;                            // 100.66 MB
  _Float16*  hcat16 = (_Float16*)(base + 100663296);           //  16.78 MB
  float*     uh     = (float*)(base + 117440512);              //  20.97 MB
  _Float16*  A16    = (_Float16*)(base + 117440512);           //  alias uh
  _Float16*  Bw16   = (_Float16*)(base + 138412032);           //   0.49 MB
  _Float16*  WcT    = (_Float16*)(base + 138903552);           //   0.08 MB

  hipLaunchKernelGGL(k0_prep, dim3(33696), dim3(64), 0, stream,
                     x, emb, wif, wib, Wc, A16, Bw16, WcT);
  hipLaunchKernelGGL(k1_xproj, dim3(256, 6), dim3(256), 0, stream,
                     A16, Bw16, bif, bib, xpT);
  hipLaunchKernelGGL(k2_gru, dim3(16), dim3(256), 0, stream,
                     xpT, whf, whb, bhf, bhb, hcat16);
  hipLaunchKernelGGL(k3_uhat, dim3(256), dim3(256), 0, stream,
                     hcat16, WcT, uh);
  hipLaunchKernelGGL(k4_route, dim3(128), dim3(256), 0, stream,
                     uh, Wl, bl, out);
}

// Round 5
// 304.819 us; speedup vs baseline: 1.9641x; 1.5960x over previous
//
#include <hip/hip_runtime.h>
#include <cmath>

#define DW 300
#define HH 128
#define G3 384
#define GN 768
#define SS 256
#define NB 128
#define NC 10
#define DC 16
#define NCDC 160
#define CAP_EPS 1e-7f
#define KP 320

typedef _Float16 h8v __attribute__((ext_vector_type(8)));
typedef _Float16 h4v __attribute__((ext_vector_type(4)));
typedef float f32x4 __attribute__((ext_vector_type(4)));

__device__ __forceinline__ float sigmoidf_(float x) {
  return 1.0f / (1.0f + __expf(-x));
}
__device__ __forceinline__ float tanhf_(float x) {
  float e = __expf(2.0f * x);
  return 1.0f - 2.0f / (e + 1.0f);
}
// LDS-only barrier: don't drain vmcnt, so global loads/stores stay in flight.
__device__ __forceinline__ void bar_lds() {
  asm volatile("s_waitcnt lgkmcnt(0)\n\ts_barrier" ::: "memory");
}

// ---------------------------------------------------------------------------
// K0: gather emb rows -> A16[32768][320] fp16 (K padded 300->320 with zeros),
// convert w_ih (f+b) -> Bw16[768][320], transpose W_cap -> WcT[160][256].
// ---------------------------------------------------------------------------
__global__ __launch_bounds__(64) void k0_prep(
    const int* __restrict__ x, const float* __restrict__ emb,
    const float* __restrict__ wif, const float* __restrict__ wib,
    const float* __restrict__ Wc,
    _Float16* __restrict__ A16, _Float16* __restrict__ Bw16,
    _Float16* __restrict__ WcT)
{
  const int row = blockIdx.x;
  const int t = threadIdx.x;
  if (row < 33536) {
    const float* __restrict__ src;
    _Float16* __restrict__ dst;
    if (row < 32768) {
      src = emb + (size_t)x[(row & 127) * SS + (row >> 7)] * DW;
      dst = A16 + (size_t)row * KP;
    } else {
      const int n = row - 32768;
      src = (n < G3) ? (wif + (size_t)n * DW) : (wib + (size_t)(n - G3) * DW);
      dst = Bw16 + (size_t)n * KP;
    }
#pragma unroll
    for (int p = 0; p < 2; ++p) {
      const int idx = p * 64 + t;
      if (idx < 75) {
        const float4 v = *(const float4*)(src + idx * 4);
        h4v o = {(_Float16)v.x, (_Float16)v.y, (_Float16)v.z, (_Float16)v.w};
        *(h4v*)(dst + idx * 4) = o;
      }
    }
    if (t < 5) {
      h4v z = {(_Float16)0.f, (_Float16)0.f, (_Float16)0.f, (_Float16)0.f};
      *(h4v*)(dst + 300 + t * 4) = z;
    }
  } else {
    const int n = row - 33536;   // 0..159
    _Float16* __restrict__ dst = WcT + (size_t)n * 256;
#pragma unroll
    for (int p = 0; p < 4; ++p) {
      const int k = p * 64 + t;
      dst[k] = (_Float16)Wc[(size_t)k * NCDC + n];
    }
  }
}

// ---------------------------------------------------------------------------
// K1: fp16 MFMA GEMM for x-projection.
// m-tile (128) == one timestep s, all 128 batches; n-tile (128) == one (dir,G).
// Epilogue: bias add + fp16 repack via LDS, store to
// xp16[dir][b][s][G*128+j]  (contiguous 768B per (seq,step) for k2).
// ---------------------------------------------------------------------------
__global__ __launch_bounds__(256) void k1_xproj(
    const _Float16* __restrict__ A16, const _Float16* __restrict__ Bw16,
    const float* __restrict__ bf, const float* __restrict__ bb,
    _Float16* __restrict__ xp16)
{
  __shared__ __align__(16) _Float16 Asb[128 * 64];
  __shared__ __align__(16) _Float16 Bsb[128 * 64];
  __shared__ __align__(16) _Float16 Ls[128 * 132];   // repack, padded stride
  const int tid = threadIdx.x;
  const int s_idx = blockIdx.x;          // timestep
  const int n0 = blockIdx.y * 128;       // (dir, G)
  const int m0 = s_idx * 128;
  const int dir = (n0 >= G3) ? 1 : 0;
  const int G = (n0 >> 7) - dir * 3;

  const int lane = tid & 63;
  const int wv = tid >> 6, wm = wv >> 1, wn = wv & 1;
  const int fr = lane & 15, kc4 = lane >> 4;

  const int srow = tid >> 3;   // 0..31 (+i*32)
  const int sch  = tid & 7;    // 16B chunk within 128B row

  f32x4 acc[4][4];
#pragma unroll
  for (int i = 0; i < 4; ++i)
#pragma unroll
    for (int j = 0; j < 4; ++j) acc[i][j] = (f32x4){0.f, 0.f, 0.f, 0.f};

  h8v ra[4], rb[4];
#pragma unroll
  for (int i = 0; i < 4; ++i) {
    const int r = i * 32 + srow;
    ra[i] = *(const h8v*)(A16 + (size_t)(m0 + r) * KP + sch * 8);
    rb[i] = *(const h8v*)(Bw16 + (size_t)(n0 + r) * KP + sch * 8);
  }

  for (int kt = 0; kt < 5; ++kt) {
    if (kt) bar_lds();                    // prev frag reads done
#pragma unroll
    for (int i = 0; i < 4; ++i) {
      const int r = i * 32 + srow;
      const int off = (r * 128 + sch * 16) ^ ((r & 7) << 4);
      *(h8v*)((char*)Asb + off) = ra[i];
      *(h8v*)((char*)Bsb + off) = rb[i];
    }
    if (kt < 4) {
      const int kb = (kt + 1) * 64;
#pragma unroll
      for (int i = 0; i < 4; ++i) {
        const int r = i * 32 + srow;
        ra[i] = *(const h8v*)(A16 + (size_t)(m0 + r) * KP + kb + sch * 8);
        rb[i] = *(const h8v*)(Bw16 + (size_t)(n0 + r) * KP + kb + sch * 8);
      }
    }
    bar_lds();                            // staged tile visible

    h8v af[4][2], bfv[4][2];
#pragma unroll
    for (int mf = 0; mf < 4; ++mf) {
      const int rA = wm * 64 + mf * 16 + fr;
#pragma unroll
      for (int ks = 0; ks < 2; ++ks) {
        const int off = (rA * 128 + ks * 64 + kc4 * 16) ^ ((rA & 7) << 4);
        af[mf][ks] = *(const h8v*)((const char*)Asb + off);
      }
    }
#pragma unroll
    for (int nf = 0; nf < 4; ++nf) {
      const int rB = wn * 64 + nf * 16 + fr;
#pragma unroll
      for (int ks = 0; ks < 2; ++ks) {
        const int off = (rB * 128 + ks * 64 + kc4 * 16) ^ ((rB & 7) << 4);
        bfv[nf][ks] = *(const h8v*)((const char*)Bsb + off);
      }
    }
#pragma unroll
    for (int ks = 0; ks < 2; ++ks)
#pragma unroll
      for (int mf = 0; mf < 4; ++mf)
#pragma unroll
        for (int nf = 0; nf < 4; ++nf)
          acc[mf][nf] = __builtin_amdgcn_mfma_f32_16x16x32_f16(
              af[mf][ks], bfv[nf][ks], acc[mf][nf], 0, 0, 0);
  }

  // ---- epilogue: bias + fp16 repack in LDS, then coalesced store ----
  const float* __restrict__ bsrc = (n0 < G3) ? (bf + n0) : (bb + (n0 - G3));
  float bval[4];
#pragma unroll
  for (int nf = 0; nf < 4; ++nf) bval[nf] = bsrc[wn * 64 + nf * 16 + fr];

#pragma unroll
  for (int mf = 0; mf < 4; ++mf)
#pragma unroll
    for (int e = 0; e < 4; ++e) {
      const int r = wm * 64 + mf * 16 + kc4 * 4 + e;   // batch b
#pragma unroll
      for (int nf = 0; nf < 4; ++nf) {
        const int c = wn * 64 + nf * 16 + fr;          // j within gate
        Ls[r * 132 + c] = (_Float16)(acc[mf][nf][e] + bval[nf]);
      }
    }
  __syncthreads();

  // 256 threads: unit = (row b, half): 128B contiguous per unit
  {
    const int r = tid >> 1;
    const int hf = tid & 1;
    _Float16* __restrict__ dst =
        xp16 + ((size_t)(dir * NB + r) * SS + s_idx) * G3 + G * 128 + hf * 64;
    const _Float16* srcl = &Ls[r * 132 + hf * 64];
#pragma unroll
    for (int i = 0; i < 8; ++i)
      *(h8v*)(dst + i * 8) = *(const h8v*)(srcl + i * 8);
  }
}

// ---------------------------------------------------------------------------
// K2: GRU recurrence via MFMA, batch-1 per block: 256 blocks x 4 waves.
// Wave wv holds w_hh^T fragments for j-tiles {2wv,2wv+1} (all 3 gates) in
// VGPRs. h[128] fp16 lives in 256B of LDS. Per step: 4 ds_read_b128 (A-frag,
// row 0 = the sequence), 24 MFMA, gates on lanes 0-15, h_new -> LDS + global.
// xp read from xp16[seq][s][384] (fp16, contiguous), prefetched 1 step.
// ---------------------------------------------------------------------------
__global__ __launch_bounds__(256) void k2_gru(
    const _Float16* __restrict__ xp16,
    const float* __restrict__ whf, const float* __restrict__ whb,
    const float* __restrict__ bhf, const float* __restrict__ bhb,
    _Float16* __restrict__ hcat16)
{
  const int blk = blockIdx.x;      // 0..255
  const int dir = blk >> 7;
  const int b   = blk & 127;
  const int tid = threadIdx.x;
  const int lane = tid & 63;
  const int wv = tid >> 6;         // 0..3
  const int fr = lane & 15;
  const int qq = lane >> 4;

  const float* __restrict__ wh = dir ? whb : whf;
  const float* __restrict__ bh = dir ? bhb : bhf;

  // B fragments (w_hh^T) + biases, persistent
  h8v wB[2][3][4];
  float bias_[2][3];
#pragma unroll
  for (int jt = 0; jt < 2; ++jt) {
    const int jg = 2 * wv + jt;
#pragma unroll
    for (int G = 0; G < 3; ++G) {
      const int row = G * HH + jg * 16 + fr;
      const float* __restrict__ p = wh + (size_t)row * HH;
#pragma unroll
      for (int kc = 0; kc < 4; ++kc) {
        const float* q = p + kc * 32 + qq * 8;
        const float4 u0 = *(const float4*)(q);
        const float4 u1 = *(const float4*)(q + 4);
        wB[jt][G][kc] = (h8v){(_Float16)u0.x, (_Float16)u0.y, (_Float16)u0.z,
                              (_Float16)u0.w, (_Float16)u1.x, (_Float16)u1.y,
                              (_Float16)u1.z, (_Float16)u1.w};
      }
      bias_[jt][G] = bh[G * HH + jg * 16 + fr];
    }
  }

  __shared__ __align__(16) _Float16 h16[HH];   // 256 B
  if (tid < 16) *(h8v*)(h16 + tid * 8) = (h8v){0, 0, 0, 0, 0, 0, 0, 0};
  __syncthreads();

  const _Float16* __restrict__ xseq =
      xp16 + (size_t)(dir * NB + b) * SS * G3;

  int s = dir ? (SS - 1) : 0;
  const int stp = dir ? -1 : 1;

  _Float16 xv[2][3];
#pragma unroll
  for (int jt = 0; jt < 2; ++jt)
#pragma unroll
    for (int G = 0; G < 3; ++G)
      xv[jt][G] = xseq[(size_t)s * G3 + G * 128 + (2 * wv + jt) * 16 + fr];

  float hold[2] = {0.f, 0.f};

  for (int it = 0; it < SS; ++it) {
    const int s_cur = s;

    // A fragments: row0 = h; address independent of fr (broadcast groups)
    h8v afr[4];
#pragma unroll
    for (int kc = 0; kc < 4; ++kc)
      afr[kc] = *(const h8v*)((const char*)h16 + kc * 64 + qq * 16);

    // current x (convert), then prefetch next step
    float xc[2][3];
#pragma unroll
    for (int jt = 0; jt < 2; ++jt)
#pragma unroll
      for (int G = 0; G < 3; ++G) xc[jt][G] = (float)xv[jt][G];
    if (it < SS - 1) {
      s += stp;
#pragma unroll
      for (int jt = 0; jt < 2; ++jt)
#pragma unroll
        for (int G = 0; G < 3; ++G)
          xv[jt][G] =
              xseq[(size_t)s * G3 + G * 128 + (2 * wv + jt) * 16 + fr];
    }

    f32x4 acc[2][3];
#pragma unroll
    for (int jt = 0; jt < 2; ++jt) {
      acc[jt][0] = (f32x4){xc[jt][0] + bias_[jt][0], 0.f, 0.f, 0.f};
      acc[jt][1] = (f32x4){xc[jt][1] + bias_[jt][1], 0.f, 0.f, 0.f};
      acc[jt][2] = (f32x4){bias_[jt][2], 0.f, 0.f, 0.f};
#pragma unroll
      for (int G = 0; G < 3; ++G)
#pragma unroll
        for (int kc = 0; kc < 4; ++kc)
          acc[jt][G] = __builtin_amdgcn_mfma_f32_16x16x32_f16(
              afr[kc], wB[jt][G][kc], acc[jt][G], 0, 0, 0);
    }

    bar_lds();   // all waves' h-frag reads complete

    if (qq == 0) {   // D row 0 lives on lanes 0..15, reg e=0
#pragma unroll
      for (int jt = 0; jt < 2; ++jt) {
        const float r = sigmoidf_(acc[jt][0][0]);
        const float z = sigmoidf_(acc[jt][1][0]);
        const float n = tanhf_(xc[jt][2] + r * acc[jt][2][0]);
        const float hnew = (1.f - z) * n + z * hold[jt];
        hold[jt] = hnew;
        const int j = (2 * wv + jt) * 16 + fr;
        const _Float16 hv = (_Float16)hnew;
        h16[j] = hv;
        hcat16[((size_t)b * SS + s_cur) * 256 + dir * HH + j] = hv;
      }
    }
    bar_lds();   // h_new visible for next step
  }
}

// ---------------------------------------------------------------------------
// K3: uh[m][n] = sum_k hcat16[m][k] * Wc[k][n]  (fp16 MFMA)
// 128-M tile x full N=160, K=256 staged whole in 64KB swizzled LDS.
// ---------------------------------------------------------------------------
__global__ __launch_bounds__(256) void k3_uhat(
    const _Float16* __restrict__ hcat16, const _Float16* __restrict__ WcT,
    float* __restrict__ uh)
{
  __shared__ __align__(16) _Float16 Hs[128 * 256];   // 64KB
  const int tid = threadIdx.x;
  const int m0 = blockIdx.x * 128;
  const int lane = tid & 63, wv = tid >> 6;
  const int fr = lane & 15, qq = lane >> 4;

  const int srow = tid >> 5;   // 0..7
  const int sch  = tid & 31;   // 16B chunk of 512B row
#pragma unroll
  for (int i = 0; i < 16; ++i) {
    const int r = i * 8 + srow;
    const h8v v = *(const h8v*)(hcat16 + (size_t)(m0 + r) * 256 + sch * 8);
    const int off = (r * 512 + sch * 16) ^ ((r & 7) << 4);
    *(h8v*)((char*)Hs + off) = v;
  }
  __syncthreads();

  f32x4 acc[2][10];
#pragma unroll
  for (int mt = 0; mt < 2; ++mt)
#pragma unroll
    for (int nt = 0; nt < 10; ++nt) acc[mt][nt] = (f32x4){0.f, 0.f, 0.f, 0.f};

#pragma unroll
  for (int kc = 0; kc < 8; ++kc) {
    h8v bf_[10];
#pragma unroll
    for (int nt = 0; nt < 10; ++nt)
      bf_[nt] = *(const h8v*)(WcT + (size_t)(nt * 16 + fr) * 256 + kc * 32 + qq * 8);
    h8v af[2];
#pragma unroll
    for (int mt = 0; mt < 2; ++mt) {
      const int rA = wv * 32 + mt * 16 + fr;
      const int off = (rA * 512 + kc * 64 + qq * 16) ^ ((rA & 7) << 4);
      af[mt] = *(const h8v*)((const char*)Hs + off);
    }
#pragma unroll
    for (int mt = 0; mt < 2; ++mt)
#pragma unroll
      for (int nt = 0; nt < 10; ++nt)
        acc[mt][nt] = __builtin_amdgcn_mfma_f32_16x16x32_f16(
            af[mt], bf_[nt], acc[mt][nt], 0, 0, 0);
  }

#pragma unroll
  for (int mt = 0; mt < 2; ++mt)
#pragma unroll
    for (int nt = 0; nt < 10; ++nt)
#pragma unroll
      for (int e = 0; e < 4; ++e) {
        const int m = m0 + wv * 32 + mt * 16 + qq * 4 + e;
        uh[(size_t)m * NCDC + nt * 16 + fr] = acc[mt][nt][e];
      }
}

// ---------------------------------------------------------------------------
// K4: dynamic routing + final linear. One block per batch element.
// ---------------------------------------------------------------------------
__global__ __launch_bounds__(256) void k4_route(
    const float* __restrict__ uhat, const float* __restrict__ Wl,
    const float* __restrict__ bl, float* __restrict__ outp)
{
  const int b = blockIdx.x;
  const int t = threadIdx.x;
  __shared__ float blog[NC][SS + 1];
  __shared__ float cbuf[NC][SS + 1];
  __shared__ float vout[NC][DC];
  __shared__ float red0[256], red1[256];

  const float* __restrict__ u = uhat + (size_t)b * SS * NCDC;

#pragma unroll
  for (int i = 0; i < NC; ++i) blog[i][t] = 0.f;
  __syncthreads();

  const int ci = t >> 4, ck = t & 15;
  float myval = 0.f;

  for (int it = 0; it < 5; ++it) {
    float m = blog[0][t];
#pragma unroll
    for (int i = 1; i < NC; ++i) m = fmaxf(m, blog[i][t]);
    float e[NC];
    float sum = 0.f;
#pragma unroll
    for (int i = 0; i < NC; ++i) { e[i] = __expf(blog[i][t] - m); sum += e[i]; }
    const float inv = 1.0f / sum;
#pragma unroll
    for (int i = 0; i < NC; ++i) cbuf[i][t] = e[i] * inv;
    __syncthreads();

    if (t < NCDC) {
      float acc = 0.f;
#pragma unroll 4
      for (int jj = 0; jj < SS; ++jj)
        acc += cbuf[ci][jj] * u[(size_t)jj * NCDC + t];
      float ss = acc * acc;
      ss += __shfl_xor(ss, 1);
      ss += __shfl_xor(ss, 2);
      ss += __shfl_xor(ss, 4);
      ss += __shfl_xor(ss, 8);
      myval = acc / sqrtf(ss + CAP_EPS);
      vout[ci][ck] = myval;
    }
    __syncthreads();

    if (it < 4) {
      const float* ur = u + (size_t)t * NCDC;
#pragma unroll
      for (int i = 0; i < NC; ++i) {
        float dot = 0.f;
#pragma unroll
        for (int k = 0; k < DC; ++k) dot += ur[i * DC + k] * vout[i][k];
        blog[i][t] += dot;
      }
      __syncthreads();
    }
  }

  float p0 = 0.f, p1 = 0.f;
  if (t < NCDC) { p0 = myval * Wl[2 * t]; p1 = myval * Wl[2 * t + 1]; }
  red0[t] = p0; red1[t] = p1;
  __syncthreads();
  for (int off = 128; off >= 1; off >>= 1) {
    if (t < off) { red0[t] += red0[t + off]; red1[t] += red1[t + off]; }
    __syncthreads();
  }
  if (t == 0) {
    outp[2 * b + 0] = red0[0] + bl[0];
    outp[2 * b + 1] = red1[0] + bl[1];
  }
}

extern "C" void kernel_launch(void* const* d_in, const int* in_sizes, int n_in,
                              void* d_out, int out_size, void* d_ws, size_t ws_size,
                              hipStream_t stream) {
  (void)in_sizes; (void)n_in; (void)out_size; (void)ws_size;
  const int*   x    = (const int*)  d_in[0];
  const float* emb  = (const float*)d_in[1];
  const float* wif  = (const float*)d_in[2];
  const float* whf  = (const float*)d_in[3];
  const float* bif  = (const float*)d_in[4];
  const float* bhf  = (const float*)d_in[5];
  const float* wib  = (const float*)d_in[6];
  const float* whb  = (const float*)d_in[7];
  const float* bib  = (const float*)d_in[8];
  const float* bhb  = (const float*)d_in[9];
  const float* Wc   = (const float*)d_in[10];
  const float* Wl   = (const float*)d_in[11];
  const float* bl   = (const float*)d_in[12];
  float* out = (float*)d_out;

  char* base = (char*)d_ws;
  _Float16* xp16   = (_Float16*)base;                       //  50.33 MB
  _Float16* hcat16 = (_Float16*)(base + 50331648);          //  16.78 MB
  float*    uh     = (float*)   (base + 67108864);          //  20.97 MB
  _Float16* A16    = (_Float16*)(base + 88080384);          //  20.97 MB
  _Float16* Bw16   = (_Float16*)(base + 109051904);         //   0.49 MB
  _Float16* WcT    = (_Float16*)(base + 109543424);         //   0.08 MB

  hipLaunchKernelGGL(k0_prep, dim3(33696), dim3(64), 0, stream,
                     x, emb, wif, wib, Wc, A16, Bw16, WcT);
  hipLaunchKernelGGL(k1_xproj, dim3(256, 6), dim3(256), 0, stream,
                     A16, Bw16, bif, bib, xp16);
  hipLaunchKernelGGL(k2_gru, dim3(256), dim3(256), 0, stream,
                     xp16, whf, whb, bhf, bhb, hcat16);
  hipLaunchKernelGGL(k3_uhat, dim3(256), dim3(256), 0, stream,
                     hcat16, WcT, uh);
  hipLaunchKernelGGL(k4_route, dim3(128), dim3(256), 0, stream,
                     uh, Wl, bl, out);
}